// Round 7
// baseline (330.767 us; speedup 1.0000x reference)
//
#include <hip/hip_runtime.h>
#include <hip/hip_bf16.h>

#define N 8192
#define FIN 512
#define FOUT 256

typedef __attribute__((ext_vector_type(8))) short bf16x8;
typedef __attribute__((ext_vector_type(4))) float f32x4;

__device__ __forceinline__ unsigned short f2bf(float x) {
  unsigned int u = __float_as_uint(x);
  return (unsigned short)((u + 0x7FFFu + ((u >> 16) & 1u)) >> 16);
}

// ---------------------------------------------------------------------------
// K1: h = features(8192x512) @ W(512x256), fp32 vector GEMM, 64x64 tile.
// Epilogue also writes hT (bf16, [FOUT][N]) for K4's B-operand staging.
// ---------------------------------------------------------------------------
__global__ __launch_bounds__(256) void gat_k1_gemm_h(
    const float* __restrict__ A, const float* __restrict__ W,
    float* __restrict__ h, unsigned short* __restrict__ hT) {
  __shared__ __align__(16) float As[16][68];
  __shared__ __align__(16) float Bs[16][64];
  const int tid = threadIdx.x;
  const int tx = tid & 15, ty = tid >> 4;
  const int nb = blockIdx.x * 64, mb = blockIdx.y * 64;
  float acc[4][4] = {};
  for (int k0 = 0; k0 < FIN; k0 += 16) {
#pragma unroll
    for (int i = 0; i < 4; ++i) {
      int e = tid + 256 * i;
      int m = e >> 4, k = e & 15;
      As[k][m] = A[(size_t)(mb + m) * FIN + k0 + k];
      int n2 = e & 63, k2 = e >> 6;
      Bs[k2][n2] = W[(size_t)(k0 + k2) * FOUT + nb + n2];
    }
    __syncthreads();
#pragma unroll
    for (int k = 0; k < 16; ++k) {
      float4 av = *reinterpret_cast<const float4*>(&As[k][ty * 4]);
      float4 bv = *reinterpret_cast<const float4*>(&Bs[k][tx * 4]);
      float aa[4] = {av.x, av.y, av.z, av.w};
      float bb[4] = {bv.x, bv.y, bv.z, bv.w};
#pragma unroll
      for (int i = 0; i < 4; ++i)
#pragma unroll
        for (int j = 0; j < 4; ++j) acc[i][j] = fmaf(aa[i], bb[j], acc[i][j]);
    }
    __syncthreads();
  }
#pragma unroll
  for (int i = 0; i < 4; ++i) {
    int m = mb + ty * 4 + i;
#pragma unroll
    for (int j = 0; j < 4; ++j) {
      int n = nb + tx * 4 + j;
      h[(size_t)m * FOUT + n] = acc[i][j];
      hT[(size_t)n * N + m] = f2bf(acc[i][j]);
    }
  }
}

// ---------------------------------------------------------------------------
// K2: hs[i] = h[i,:]@a[:256], hd[i] = h[i,:]@a[256:]. One wave per row.
// ---------------------------------------------------------------------------
__global__ __launch_bounds__(256) void gat_k2_hshd(
    const float* __restrict__ h, const float* __restrict__ a,
    float* __restrict__ hs, float* __restrict__ hd) {
  const int wid = threadIdx.x >> 6;
  const int lane = threadIdx.x & 63;
  const int row = blockIdx.x * 4 + wid;
  float ps = 0.f, pd = 0.f;
#pragma unroll
  for (int i = 0; i < 4; ++i) {
    int c = lane + 64 * i;
    float v = h[(size_t)row * FOUT + c];
    ps += v * a[c];
    pd += v * a[FOUT + c];
  }
#pragma unroll
  for (int off = 32; off >= 1; off >>= 1) {
    ps += __shfl_down(ps, off);
    pd += __shfl_down(pd, off);
  }
  if (lane == 0) {
    hs[row] = ps;
    hd[row] = pd;
  }
}

// ---------------------------------------------------------------------------
// K3 v2: masked softmax rows (no max-subtraction: logits O(+-8), exp f32-safe,
// validated R4/R5 with identical absmax). One streaming adj pass per row.
// ALSO emits: adjacency bitmask `bits` ([row][1024 B], bit j of byte c = col
// c*8+j) and per-row inv denominator — together 8 MB of state that lets K4
// RECOMPUTE attention instead of re-reading 268 MB.
// ---------------------------------------------------------------------------
__global__ __launch_bounds__(256) void gat_k3_attn(
    const float* __restrict__ adj, const float* __restrict__ hs,
    const float* __restrict__ hd, float* __restrict__ att,
    unsigned char* __restrict__ bits, float* __restrict__ invd) {
  __shared__ __align__(16) float hd_s[N];  // 32 KB
  __shared__ float red[4];
  const int tid = threadIdx.x;
  const int lane = tid & 63, wid = tid >> 6;
#pragma unroll
  for (int i = 0; i < 8; ++i) {
    int j = tid * 4 + 1024 * i;
    *reinterpret_cast<float4*>(&hd_s[j]) =
        *reinterpret_cast<const float4*>(&hd[j]);
  }
  __syncthreads();
  const int row0 = blockIdx.x * 8;
  for (int r = 0; r < 8; ++r) {
    const int row = row0 + r;
    const float hsv = hs[row];
    const float* arow = adj + (size_t)row * N;
    float4 l[8];
    unsigned int nibs = 0;  // nibble per i (4 cols each)
    float s = 0.f;
#pragma unroll
    for (int i = 0; i < 8; ++i) {
      int j = tid * 4 + 1024 * i;
      float4 a4 = *reinterpret_cast<const float4*>(&arow[j]);
      float4 h4 = *reinterpret_cast<const float4*>(&hd_s[j]);
      unsigned int b0 = (a4.x != 0.f) ? 1u : 0u;
      unsigned int b1 = (a4.y != 0.f) ? 1u : 0u;
      unsigned int b2 = (a4.z != 0.f) ? 1u : 0u;
      unsigned int b3 = (a4.w != 0.f) ? 1u : 0u;
      float x0 = hsv + h4.x, x1 = hsv + h4.y;
      float x2 = hsv + h4.z, x3 = hsv + h4.w;
      float4 e;
      e.x = b0 ? __expf(fmaxf(x0, 0.01f * x0)) : 0.f;
      e.y = b1 ? __expf(fmaxf(x1, 0.01f * x1)) : 0.f;
      e.z = b2 ? __expf(fmaxf(x2, 0.01f * x2)) : 0.f;
      e.w = b3 ? __expf(fmaxf(x3, 0.01f * x3)) : 0.f;
      l[i] = e;
      s += e.x + e.y + e.z + e.w;
      nibs |= (b0 | (b1 << 1) | (b2 << 2) | (b3 << 3)) << (4 * i);
    }
#pragma unroll
    for (int off = 32; off >= 1; off >>= 1) s += __shfl_down(s, off);
    if (lane == 0) red[wid] = s;
    __syncthreads();
    s = red[0] + red[1] + red[2] + red[3];
    __syncthreads();
    const float inv = 1.f / s;
    // bitmask: pair nibbles from even/odd threads -> byte per 8 cols
    unsigned int part = __shfl_xor(nibs, 1);
    if (!(tid & 1)) {
      unsigned char* bp = bits + (size_t)row * 1024 + (tid >> 1);
#pragma unroll
      for (int i = 0; i < 8; ++i)
        bp[128 * i] = (unsigned char)(((nibs >> (4 * i)) & 0xF) |
                                      (((part >> (4 * i)) & 0xF) << 4));
    }
    if (tid == 0) invd[row] = inv;
    float* orow = att + (size_t)row * N;
#pragma unroll
    for (int i = 0; i < 8; ++i) {
      float4 e = l[i];
      e.x *= inv; e.y *= inv; e.z *= inv; e.w *= inv;
      *reinterpret_cast<float4*>(&orow[tid * 4 + 1024 * i]) = e;
    }
  }
}

// ---------------------------------------------------------------------------
// K4 v4: output = attention @ h, with the A-operand RECOMPUTED (not read).
// BM=64, BN=128, full K per block -> grid = 128x2 = 256 blocks, 512 threads
// (8 waves, wave tile 32x32), LDS 48 KB -> 2 blocks/CU. No atomics.
// Per K-step t: thread (ar=tid>>3, kg=tid&7) loads the row's u64 tile-mask
// (8-lane broadcast, L1), hd[t*64+kg*8..+8) (L1, 32 KB resident), computes
// 8 p = mask ? exp(leaky(hs+hd))*inv : 0, packs bf16x8 -> XOR-swizzled As.
// B reg-staged from L2-resident hT (pre-swizzled source, R6-proven).
// Double-buffered, one barrier per step. HBM traffic ~16 MB total.
// ---------------------------------------------------------------------------
__global__ __launch_bounds__(512, 2) void gat_k4_out(
    const unsigned long long* __restrict__ bits, const float* __restrict__ hs,
    const float* __restrict__ hd, const float* __restrict__ invd,
    const unsigned short* __restrict__ hT, float* __restrict__ C) {
  __shared__ __align__(16) unsigned short As[2][64 * 64];   // 2 x 8 KB
  __shared__ __align__(16) unsigned short Bs[2][128 * 64];  // 2 x 16 KB
  const int tid = threadIdx.x;
  const int lane = tid & 63;
  const int wid = tid >> 6;
  const int wm = wid >> 2, wn = wid & 3;  // wave tile 32(M) x 32(N)
  const int g = lane >> 4, rsel = lane & 15;
  const int id = blockIdx.x;
  const int nh = id & 1;        // XCD x caches only hT half nh = x&1 (2 MB)
  const int row0 = (id >> 1) * 64;
  const int nb = nh * 128;

  // A-generation assignment: row ar (0..63), k-group kg (8 cols of 8)
  const int ar = tid >> 3, kg = tid & 7;
  const float hsv = hs[row0 + ar];
  const float inv = invd[row0 + ar];
  const unsigned long long* mrow = bits + (size_t)(row0 + ar) * 128;
  const int awbyte = ar * 128 + ((kg ^ (ar & 7)) << 4);

  // B staging (2 uint4/thread), source pre-swizzled, LDS linear
  const unsigned short* bsrc[2];
  int bofs[2];
#pragma unroll
  for (int i = 0; i < 2; ++i) {
    int s = tid + 512 * i;
    int n = s >> 3, kb = s & 7;
    bsrc[i] = hT + (size_t)(nb + n) * N + (kb ^ (n & 7)) * 8;
    bofs[i] = s * 16;
  }

#define GEN_A(T, PK)                                                       \
  {                                                                        \
    unsigned long long mm = mrow[(T)];                                     \
    unsigned int mb8 = (unsigned int)(mm >> (kg * 8)) & 0xFFu;             \
    const float* hp = hd + (T) * 64 + kg * 8;                              \
    float4 h40 = *reinterpret_cast<const float4*>(hp);                     \
    float4 h41 = *reinterpret_cast<const float4*>(hp + 4);                 \
    float x0 = hsv + h40.x, x1 = hsv + h40.y;                              \
    float x2 = hsv + h40.z, x3 = hsv + h40.w;                              \
    float x4 = hsv + h41.x, x5 = hsv + h41.y;                              \
    float x6 = hsv + h41.z, x7 = hsv + h41.w;                              \
    float p0 = (mb8 & 1u) ? __expf(fmaxf(x0, 0.01f * x0)) * inv : 0.f;     \
    float p1 = (mb8 & 2u) ? __expf(fmaxf(x1, 0.01f * x1)) * inv : 0.f;     \
    float p2 = (mb8 & 4u) ? __expf(fmaxf(x2, 0.01f * x2)) * inv : 0.f;     \
    float p3 = (mb8 & 8u) ? __expf(fmaxf(x3, 0.01f * x3)) * inv : 0.f;     \
    float p4 = (mb8 & 16u) ? __expf(fmaxf(x4, 0.01f * x4)) * inv : 0.f;    \
    float p5 = (mb8 & 32u) ? __expf(fmaxf(x5, 0.01f * x5)) * inv : 0.f;    \
    float p6 = (mb8 & 64u) ? __expf(fmaxf(x6, 0.01f * x6)) * inv : 0.f;    \
    float p7 = (mb8 & 128u) ? __expf(fmaxf(x7, 0.01f * x7)) * inv : 0.f;   \
    PK.x = (unsigned)f2bf(p0) | ((unsigned)f2bf(p1) << 16);                \
    PK.y = (unsigned)f2bf(p2) | ((unsigned)f2bf(p3) << 16);                \
    PK.z = (unsigned)f2bf(p4) | ((unsigned)f2bf(p5) << 16);                \
    PK.w = (unsigned)f2bf(p6) | ((unsigned)f2bf(p7) << 16);                \
  }

  f32x4 acc[2][2] = {};
  uint4 apk, bB0, bB1;

  // prologue: tile 0
  GEN_A(0, apk);
  bB0 = *reinterpret_cast<const uint4*>(bsrc[0]);
  bB1 = *reinterpret_cast<const uint4*>(bsrc[1]);
  *reinterpret_cast<uint4*>(reinterpret_cast<char*>(As[0]) + awbyte) = apk;
  *reinterpret_cast<uint4*>(reinterpret_cast<char*>(Bs[0]) + bofs[0]) = bB0;
  *reinterpret_cast<uint4*>(reinterpret_cast<char*>(Bs[0]) + bofs[1]) = bB1;

  int cur = 0;
  for (int t = 0; t < 128; ++t) {
    if (t < 127) {  // prefetch/recompute next tile before the barrier
      const int knext = (t + 1) * 64;
      bB0 = *reinterpret_cast<const uint4*>(bsrc[0] + knext);
      bB1 = *reinterpret_cast<const uint4*>(bsrc[1] + knext);
      GEN_A(t + 1, apk);
    }
    __syncthreads();
    const char* Ac = reinterpret_cast<const char*>(As[cur]);
    const char* Bc = reinterpret_cast<const char*>(Bs[cur]);
#pragma unroll
    for (int ks = 0; ks < 2; ++ks) {
      bf16x8 af[2], bg[2];
#pragma unroll
      for (int f = 0; f < 2; ++f) {
        int rr = wm * 32 + f * 16 + rsel;
        af[f] = *reinterpret_cast<const bf16x8*>(
            Ac + rr * 128 + ((ks * 64 + g * 16) ^ ((rr & 7) << 4)));
        int n = wn * 32 + f * 16 + rsel;
        bg[f] = *reinterpret_cast<const bf16x8*>(
            Bc + n * 128 + ((ks * 64 + g * 16) ^ ((n & 7) << 4)));
      }
#pragma unroll
      for (int i = 0; i < 2; ++i)
#pragma unroll
        for (int j = 0; j < 2; ++j)
          acc[i][j] = __builtin_amdgcn_mfma_f32_16x16x32_bf16(af[i], bg[j],
                                                              acc[i][j], 0, 0, 0);
    }
    if (t < 127) {
      char* An = reinterpret_cast<char*>(As[cur ^ 1]);
      char* Bn = reinterpret_cast<char*>(Bs[cur ^ 1]);
      *reinterpret_cast<uint4*>(An + awbyte) = apk;
      *reinterpret_cast<uint4*>(Bn + bofs[0]) = bB0;
      *reinterpret_cast<uint4*>(Bn + bofs[1]) = bB1;
      cur ^= 1;
    }
  }
#undef GEN_A
  // direct store (full K per block): C/D layout col=lane&15, row=(lane>>4)*4+reg
#pragma unroll
  for (int i = 0; i < 2; ++i)
#pragma unroll
    for (int j = 0; j < 2; ++j)
#pragma unroll
      for (int r = 0; r < 4; ++r) {
        int row = row0 + wm * 32 + i * 16 + g * 4 + r;
        int col = nb + wn * 32 + j * 16 + rsel;
        C[(size_t)row * FOUT + col] = acc[i][j][r];
      }
}

extern "C" void kernel_launch(void* const* d_in, const int* in_sizes, int n_in,
                              void* d_out, int out_size, void* d_ws, size_t ws_size,
                              hipStream_t stream) {
  const float* features = (const float*)d_in[0];
  const float* adj = (const float*)d_in[1];
  const float* W = (const float*)d_in[2];
  const float* a = (const float*)d_in[3];

  float* out = (float*)d_out;           // [N][FOUT]
  float* att = out + (size_t)N * FOUT;  // [N][N]

  char* ws = (char*)d_ws;
  float* h = (float*)ws;                                        // 8 MB
  unsigned short* hT = (unsigned short*)(ws + (size_t)8388608);  // 4 MB
  float* hs = (float*)(ws + (size_t)12582912);
  float* hd = hs + N;
  float* invd = hd + N;
  unsigned char* bits = (unsigned char*)(ws + (size_t)12582912 + 3 * N * 4);

  hipLaunchKernelGGL(gat_k1_gemm_h, dim3(FOUT / 64, N / 64), dim3(256), 0,
                     stream, features, W, h, hT);
  hipLaunchKernelGGL(gat_k2_hshd, dim3(N / 4), dim3(256), 0, stream, h, a, hs,
                     hd);
  hipLaunchKernelGGL(gat_k3_attn, dim3(N / 8), dim3(256), 0, stream, adj, hs,
                     hd, att, bits, invd);
  hipLaunchKernelGGL(gat_k4_out, dim3(256), dim3(512), 0, stream,
                     (const unsigned long long*)bits, hs, hd, invd, hT, out);
}

// Round 8
// 302.048 us; speedup vs baseline: 1.0951x; 1.0951x over previous
//
#include <hip/hip_runtime.h>
#include <hip/hip_bf16.h>

#define N 8192
#define FIN 512
#define FOUT 256

typedef __attribute__((ext_vector_type(8))) short bf16x8;
typedef __attribute__((ext_vector_type(4))) float f32x4;

__device__ __forceinline__ unsigned short f2bf(float x) {
  unsigned int u = __float_as_uint(x);
  return (unsigned short)((u + 0x7FFFu + ((u >> 16) & 1u)) >> 16);
}

__device__ __forceinline__ unsigned int pkbf2(float a, float b) {
  __hip_bfloat162 h = __float22bfloat162_rn(make_float2(a, b));
  unsigned int u;
  __builtin_memcpy(&u, &h, 4);
  return u;
}

__device__ __forceinline__ void load_lds16(const void* g, void* l) {
  __builtin_amdgcn_global_load_lds(
      (const __attribute__((address_space(1))) void*)g,
      (__attribute__((address_space(3))) void*)l, 16, 0, 0);
}

// ---------------------------------------------------------------------------
// K1: h = features(8192x512) @ W(512x256), fp32 vector GEMM, 64x64 tile.
// Epilogue also writes hT (bf16, [FOUT][N]) for K4's B-operand staging.
// ---------------------------------------------------------------------------
__global__ __launch_bounds__(256) void gat_k1_gemm_h(
    const float* __restrict__ A, const float* __restrict__ W,
    float* __restrict__ h, unsigned short* __restrict__ hT) {
  __shared__ __align__(16) float As[16][68];
  __shared__ __align__(16) float Bs[16][64];
  const int tid = threadIdx.x;
  const int tx = tid & 15, ty = tid >> 4;
  const int nb = blockIdx.x * 64, mb = blockIdx.y * 64;
  float acc[4][4] = {};
  for (int k0 = 0; k0 < FIN; k0 += 16) {
#pragma unroll
    for (int i = 0; i < 4; ++i) {
      int e = tid + 256 * i;
      int m = e >> 4, k = e & 15;
      As[k][m] = A[(size_t)(mb + m) * FIN + k0 + k];
      int n2 = e & 63, k2 = e >> 6;
      Bs[k2][n2] = W[(size_t)(k0 + k2) * FOUT + nb + n2];
    }
    __syncthreads();
#pragma unroll
    for (int k = 0; k < 16; ++k) {
      float4 av = *reinterpret_cast<const float4*>(&As[k][ty * 4]);
      float4 bv = *reinterpret_cast<const float4*>(&Bs[k][tx * 4]);
      float aa[4] = {av.x, av.y, av.z, av.w};
      float bb[4] = {bv.x, bv.y, bv.z, bv.w};
#pragma unroll
      for (int i = 0; i < 4; ++i)
#pragma unroll
        for (int j = 0; j < 4; ++j) acc[i][j] = fmaf(aa[i], bb[j], acc[i][j]);
    }
    __syncthreads();
  }
#pragma unroll
  for (int i = 0; i < 4; ++i) {
    int m = mb + ty * 4 + i;
#pragma unroll
    for (int j = 0; j < 4; ++j) {
      int n = nb + tx * 4 + j;
      h[(size_t)m * FOUT + n] = acc[i][j];
      hT[(size_t)n * N + m] = f2bf(acc[i][j]);
    }
  }
}

// ---------------------------------------------------------------------------
// K2: hs[i] = h[i,:]@a[:256], hd[i] = h[i,:]@a[256:]. One wave per row.
// ---------------------------------------------------------------------------
__global__ __launch_bounds__(256) void gat_k2_hshd(
    const float* __restrict__ h, const float* __restrict__ a,
    float* __restrict__ hs, float* __restrict__ hd) {
  const int wid = threadIdx.x >> 6;
  const int lane = threadIdx.x & 63;
  const int row = blockIdx.x * 4 + wid;
  float ps = 0.f, pd = 0.f;
#pragma unroll
  for (int i = 0; i < 4; ++i) {
    int c = lane + 64 * i;
    float v = h[(size_t)row * FOUT + c];
    ps += v * a[c];
    pd += v * a[FOUT + c];
  }
#pragma unroll
  for (int off = 32; off >= 1; off >>= 1) {
    ps += __shfl_down(ps, off);
    pd += __shfl_down(pd, off);
  }
  if (lane == 0) {
    hs[row] = ps;
    hd[row] = pd;
  }
}

// ---------------------------------------------------------------------------
// K3 v2: masked softmax rows (no max-subtraction: logits O(+-8), exp f32-safe,
// validated R4-R7, absmax identical). One streaming adj pass per row.
// Emits: att (f32, the required output), adjacency bitmask `bits`
// ([row][1024 B], bit j of byte c = col c*8+j), and li[row] = log(1/s) so K4
// can RECOMPUTE attention in bf16 instead of re-reading 268 MB.
// ---------------------------------------------------------------------------
__global__ __launch_bounds__(256) void gat_k3_attn(
    const float* __restrict__ adj, const float* __restrict__ hs,
    const float* __restrict__ hd, float* __restrict__ att,
    unsigned char* __restrict__ bits, float* __restrict__ li) {
  __shared__ __align__(16) float hd_s[N];  // 32 KB
  __shared__ float red[4];
  const int tid = threadIdx.x;
  const int lane = tid & 63, wid = tid >> 6;
#pragma unroll
  for (int i = 0; i < 8; ++i) {
    int j = tid * 4 + 1024 * i;
    *reinterpret_cast<float4*>(&hd_s[j]) =
        *reinterpret_cast<const float4*>(&hd[j]);
  }
  __syncthreads();
  const int row0 = blockIdx.x * 8;
  for (int r = 0; r < 8; ++r) {
    const int row = row0 + r;
    const float hsv = hs[row];
    const float* arow = adj + (size_t)row * N;
    float4 l[8];
    unsigned int nibs = 0;
    float s = 0.f;
#pragma unroll
    for (int i = 0; i < 8; ++i) {
      int j = tid * 4 + 1024 * i;
      float4 a4 = *reinterpret_cast<const float4*>(&arow[j]);
      float4 h4 = *reinterpret_cast<const float4*>(&hd_s[j]);
      unsigned int b0 = (a4.x != 0.f) ? 1u : 0u;
      unsigned int b1 = (a4.y != 0.f) ? 1u : 0u;
      unsigned int b2 = (a4.z != 0.f) ? 1u : 0u;
      unsigned int b3 = (a4.w != 0.f) ? 1u : 0u;
      float x0 = hsv + h4.x, x1 = hsv + h4.y;
      float x2 = hsv + h4.z, x3 = hsv + h4.w;
      float4 e;
      e.x = b0 ? __expf(fmaxf(x0, 0.01f * x0)) : 0.f;
      e.y = b1 ? __expf(fmaxf(x1, 0.01f * x1)) : 0.f;
      e.z = b2 ? __expf(fmaxf(x2, 0.01f * x2)) : 0.f;
      e.w = b3 ? __expf(fmaxf(x3, 0.01f * x3)) : 0.f;
      l[i] = e;
      s += e.x + e.y + e.z + e.w;
      nibs |= (b0 | (b1 << 1) | (b2 << 2) | (b3 << 3)) << (4 * i);
    }
#pragma unroll
    for (int off = 32; off >= 1; off >>= 1) s += __shfl_down(s, off);
    if (lane == 0) red[wid] = s;
    __syncthreads();
    s = red[0] + red[1] + red[2] + red[3];
    __syncthreads();
    const float inv = 1.f / s;
    unsigned int part = __shfl_xor(nibs, 1);
    if (!(tid & 1)) {
      unsigned char* bp = bits + (size_t)row * 1024 + (tid >> 1);
#pragma unroll
      for (int i = 0; i < 8; ++i)
        bp[128 * i] = (unsigned char)(((nibs >> (4 * i)) & 0xF) |
                                      (((part >> (4 * i)) & 0xF) << 4));
    }
    if (tid == 0) li[row] = __logf(inv);
    float* orow = att + (size_t)row * N;
#pragma unroll
    for (int i = 0; i < 8; ++i) {
      float4 e = l[i];
      e.x *= inv; e.y *= inv; e.z *= inv; e.w *= inv;
      *reinterpret_cast<float4*>(&orow[tid * 4 + 1024 * i]) = e;
    }
  }
}

// ---------------------------------------------------------------------------
// K4 v5: output = attention @ h, A-operand RECOMPUTED (~17 MB HBM total).
// BM=64, BN=64, BK=128, full K -> grid = 128 row x 4 n = 512 blocks of 512
// threads (8 waves, wave tile 16x32), LDS 64 KB -> 2 blocks/CU. No atomics.
// XCD: nq = xcd&3 so each XCD streams one 1 MB L2-resident hT quarter.
// Schedule per tile (T3 minimal recipe -- STAGE FIRST, drain covered):
//   1. issue global_load_lds B(t+1) + mask/hd loads for A-gen(t+1)
//   2. MFMA(t) from LDS  ||  A-gen(t+1) VALU (separate pipes)
//   3. ds_write A(t+1), flip, __syncthreads (vmcnt drain covered by step 2)
// A-gen: p = exp(max(hd+Ar, fma(hd,.01,Br))) with Ar=hs+li, Br=.01hs+li
// (1/s folded into exponent); mask via arg=-1e9 -> exp=0 exactly.
// ---------------------------------------------------------------------------
__global__ __launch_bounds__(512, 2) void gat_k4_out(
    const unsigned long long* __restrict__ bits, const float* __restrict__ hs,
    const float* __restrict__ hd, const float* __restrict__ li,
    const unsigned short* __restrict__ hT, float* __restrict__ C) {
  __shared__ __align__(16) unsigned short As[2][64 * 128];  // 2 x 16 KB
  __shared__ __align__(16) unsigned short Bs[2][64 * 128];  // 2 x 16 KB
  const int tid = threadIdx.x;
  const int lane = tid & 63;
  const int wid = tid >> 6;
  const int wm = wid >> 1, wn = wid & 1;  // wave tile 16(M) x 32(N)
  const int g = lane >> 4, rsel = lane & 15;
  const int id = blockIdx.x;
  const int xcd = id & 7;
  const int nq = xcd & 3;
  const int row0 = (((xcd >> 2) << 6) + (id >> 3)) * 64;
  const int nb0 = nq * 64;

  // A-gen assignment: row ar (0..63), 16-col group kq (0..7)
  const int ar = tid >> 3, kq = tid & 7;
  const float lir = li[row0 + ar];
  const float hsr = hs[row0 + ar];
  const float Ar = hsr + lir;
  const float Br = 0.01f * hsr + lir;
  const unsigned long long* mrow = bits + (size_t)(row0 + ar) * 128;
  const float* hdp = hd + kq * 16;
  const int aw0 = ar * 256 + (((kq * 2) ^ (ar & 7)) << 4);
  const int aw1 = ar * 256 + (((kq * 2 + 1) ^ (ar & 7)) << 4);

  // B staging via global_load_lds (2 slots/thread), pre-swizzled source
  const unsigned short* bsrc[2];
  int bofs[2];
#pragma unroll
  for (int i = 0; i < 2; ++i) {
    int s = tid + 512 * i;
    int n = s >> 4, sl = s & 15;
    bsrc[i] = hT + (size_t)(nb0 + n) * N + (sl ^ (n & 7)) * 8;
    bofs[i] = s * 16;
  }

#define PGEN(Y, MB) \
  __expf((MB) ? fmaxf((Y) + Ar, fmaf((Y), 0.01f, Br)) : -1e9f)

#define GEN_A(T, PKA, PKB)                                              \
  do {                                                                  \
    unsigned long long mm = mrow[2 * (T) + (kq >> 2)];                  \
    unsigned int m16 = (unsigned int)(mm >> ((kq & 3) * 16)) & 0xFFFFu; \
    const float* hp = hdp + (T) * 128;                                  \
    float4 h0 = *reinterpret_cast<const float4*>(hp);                   \
    float4 h1 = *reinterpret_cast<const float4*>(hp + 4);               \
    float4 h2 = *reinterpret_cast<const float4*>(hp + 8);               \
    float4 h3 = *reinterpret_cast<const float4*>(hp + 12);              \
    float p0 = PGEN(h0.x, m16 & 1u), p1 = PGEN(h0.y, m16 & 2u);         \
    float p2 = PGEN(h0.z, m16 & 4u), p3 = PGEN(h0.w, m16 & 8u);         \
    float p4 = PGEN(h1.x, m16 & 16u), p5 = PGEN(h1.y, m16 & 32u);       \
    float p6 = PGEN(h1.z, m16 & 64u), p7 = PGEN(h1.w, m16 & 128u);      \
    float p8 = PGEN(h2.x, m16 & 256u), p9 = PGEN(h2.y, m16 & 512u);     \
    float pa = PGEN(h2.z, m16 & 1024u), pb = PGEN(h2.w, m16 & 2048u);   \
    float pc = PGEN(h3.x, m16 & 4096u), pd = PGEN(h3.y, m16 & 8192u);   \
    float pe = PGEN(h3.z, m16 & 16384u), pf = PGEN(h3.w, m16 & 32768u); \
    PKA.x = pkbf2(p0, p1); PKA.y = pkbf2(p2, p3);                       \
    PKA.z = pkbf2(p4, p5); PKA.w = pkbf2(p6, p7);                       \
    PKB.x = pkbf2(p8, p9); PKB.y = pkbf2(pa, pb);                       \
    PKB.z = pkbf2(pc, pd); PKB.w = pkbf2(pe, pf);                       \
  } while (0)

  f32x4 acc[2] = {};
  uint4 apA, apB;

  // prologue: tile 0 staged into buf 0
  GEN_A(0, apA, apB);
  load_lds16(bsrc[0], reinterpret_cast<char*>(Bs[0]) + bofs[0]);
  load_lds16(bsrc[1], reinterpret_cast<char*>(Bs[0]) + bofs[1]);
  *reinterpret_cast<uint4*>(reinterpret_cast<char*>(As[0]) + aw0) = apA;
  *reinterpret_cast<uint4*>(reinterpret_cast<char*>(As[0]) + aw1) = apB;
  __syncthreads();

  int cur = 0;
  for (int t = 0; t < 64; ++t) {
    // 1. issue next tile's staging FIRST (latency covered by step 2)
    if (t < 63) {
      const int kel = (t + 1) * 128;
      load_lds16(bsrc[0] + kel, reinterpret_cast<char*>(Bs[cur ^ 1]) + bofs[0]);
      load_lds16(bsrc[1] + kel, reinterpret_cast<char*>(Bs[cur ^ 1]) + bofs[1]);
      GEN_A(t + 1, apA, apB);  // mask/hd loads + VALU, overlaps MFMA below
    }
    // 2. MFMA current tile from LDS
    const char* Ac = reinterpret_cast<const char*>(As[cur]);
    const char* Bc = reinterpret_cast<const char*>(Bs[cur]);
#pragma unroll
    for (int ks = 0; ks < 4; ++ks) {
      const int rr = wm * 16 + rsel;
      bf16x8 af = *reinterpret_cast<const bf16x8*>(
          Ac + rr * 256 + ((((ks * 4 + g) ^ (rr & 7))) << 4));
#pragma unroll
      for (int f = 0; f < 2; ++f) {
        const int n = wn * 32 + f * 16 + rsel;
        bf16x8 bg = *reinterpret_cast<const bf16x8*>(
            Bc + n * 256 + ((((ks * 4 + g) ^ (n & 7))) << 4));
        acc[f] = __builtin_amdgcn_mfma_f32_16x16x32_bf16(af, bg, acc[f],
                                                         0, 0, 0);
      }
    }
    // 3. write next A tile, flip, barrier (drain covered by step 2)
    if (t < 63) {
      *reinterpret_cast<uint4*>(reinterpret_cast<char*>(As[cur ^ 1]) + aw0) = apA;
      *reinterpret_cast<uint4*>(reinterpret_cast<char*>(As[cur ^ 1]) + aw1) = apB;
      cur ^= 1;
    }
    __syncthreads();
  }
#undef GEN_A
#undef PGEN
  // C store: C/D layout col=lane&15, row=(lane>>4)*4+reg
#pragma unroll
  for (int f = 0; f < 2; ++f)
#pragma unroll
    for (int r = 0; r < 4; ++r) {
      int row = row0 + wm * 16 + g * 4 + r;
      int col = nb0 + wn * 32 + f * 16 + rsel;
      C[(size_t)row * FOUT + col] = acc[f][r];
    }
}

extern "C" void kernel_launch(void* const* d_in, const int* in_sizes, int n_in,
                              void* d_out, int out_size, void* d_ws, size_t ws_size,
                              hipStream_t stream) {
  const float* features = (const float*)d_in[0];
  const float* adj = (const float*)d_in[1];
  const float* W = (const float*)d_in[2];
  const float* a = (const float*)d_in[3];

  float* out = (float*)d_out;           // [N][FOUT]
  float* att = out + (size_t)N * FOUT;  // [N][N]

  char* ws = (char*)d_ws;
  float* h = (float*)ws;                                         // 8 MB
  unsigned short* hT = (unsigned short*)(ws + (size_t)8388608);  // 4 MB
  float* hs = (float*)(ws + (size_t)12582912);
  float* hd = hs + N;
  float* li = hd + N;
  unsigned char* bits = (unsigned char*)(ws + (size_t)12582912 + 3 * N * 4);

  hipLaunchKernelGGL(gat_k1_gemm_h, dim3(FOUT / 64, N / 64), dim3(256), 0,
                     stream, features, W, h, hT);
  hipLaunchKernelGGL(gat_k2_hshd, dim3(N / 4), dim3(256), 0, stream, h, a, hs,
                     hd);
  hipLaunchKernelGGL(gat_k3_attn, dim3(N / 8), dim3(256), 0, stream, adj, hs,
                     hd, att, bits, li);
  hipLaunchKernelGGL(gat_k4_out, dim3(512), dim3(512), 0, stream,
                     (const unsigned long long*)bits, hs, hd, li, hT, out);
}